// Round 5
// baseline (268.774 us; speedup 1.0000x reference)
//
#include <hip/hip_runtime.h>
#include <math.h>

#define NL 12
#define NB 2
#define NT 2048
#define ND 2048
#define NC 4
#define NH 48
#define NBT (NB*NT)                 // 4096 tokens
#define BTD ((long)NBT*(long)ND)    // 8388608
#define TOK 8                       // tokens per block in dw_kernel
#define ATOK 8                      // tokens per block in agg_kernel
#define AGRID (NBT/ATOK)            // 512 blocks

typedef float fx4 __attribute__((ext_vector_type(4)));

__device__ __forceinline__ float gelu_exact(float x) {
    return 0.5f * x * (1.0f + erff(x * 0.70710678118654752f));
}

// Kernel 1: dw[b,t,j] = (gelu(rms(x_cur) @ w1) @ w2)[j] + static_weight[j]
__global__ __launch_bounds__(256, 2)
void dw_kernel(const float* __restrict__ xs,
               const float* __restrict__ w1,
               const float* __restrict__ w2,
               const float* __restrict__ sw,
               float* __restrict__ dw_out) {
    __shared__ float xls[TOK][ND];      // 64 KB: 8 token rows of x_current
    __shared__ float rinv_s[TOK];
    __shared__ float y_s[TOK][NH];
    const int tid  = threadIdx.x;
    const int wave = tid >> 6;
    const int lane = tid & 63;

    const float* xcur = xs + (long)(NL - 1) * BTD + (long)blockIdx.x * TOK * ND;
    const float4* src = (const float4*)xcur;
    float4* dst = (float4*)&xls[0][0];
    #pragma unroll
    for (int i = 0; i < (TOK * ND / 4) / 256; ++i)
        dst[tid + i * 256] = src[tid + i * 256];
    __syncthreads();

    #pragma unroll
    for (int tt = 0; tt < 2; ++tt) {
        const int tok = wave * 2 + tt;
        float ss = 0.f;
        for (int d = lane; d < ND; d += 64) { float v = xls[tok][d]; ss += v * v; }
        #pragma unroll
        for (int off = 32; off; off >>= 1) ss += __shfl_xor(ss, off);
        if (lane == 0) rinv_s[tok] = rsqrtf(ss * (1.0f / ND) + 1e-6f);
    }
    __syncthreads();

    float rv[TOK];
    #pragma unroll
    for (int t = 0; t < TOK; ++t) rv[t] = rinv_s[t];

    float acc[TOK][12];
    #pragma unroll
    for (int t = 0; t < TOK; ++t)
        #pragma unroll
        for (int j = 0; j < 12; ++j) acc[t][j] = 0.f;

    const int h0 = wave * 12;
    for (int d = lane; d < ND; d += 64) {
        const float* wrow = w1 + (long)d * NH + h0;
        const float4 wA = *(const float4*)(wrow);
        const float4 wB = *(const float4*)(wrow + 4);
        const float4 wC = *(const float4*)(wrow + 8);
        #pragma unroll
        for (int t = 0; t < TOK; ++t) {
            const float xv = xls[t][d] * rv[t];
            acc[t][0]  += xv * wA.x; acc[t][1]  += xv * wA.y;
            acc[t][2]  += xv * wA.z; acc[t][3]  += xv * wA.w;
            acc[t][4]  += xv * wB.x; acc[t][5]  += xv * wB.y;
            acc[t][6]  += xv * wB.z; acc[t][7]  += xv * wB.w;
            acc[t][8]  += xv * wC.x; acc[t][9]  += xv * wC.y;
            acc[t][10] += xv * wC.z; acc[t][11] += xv * wC.w;
        }
    }
    #pragma unroll
    for (int t = 0; t < TOK; ++t)
        #pragma unroll
        for (int j = 0; j < 12; ++j) {
            float v = acc[t][j];
            #pragma unroll
            for (int off = 32; off; off >>= 1) v += __shfl_xor(v, off);
            acc[t][j] = v;
        }
    if (lane == 0) {
        #pragma unroll
        for (int t = 0; t < TOK; ++t)
            #pragma unroll
            for (int j = 0; j < 12; ++j)
                y_s[t][h0 + j] = acc[t][j];
    }
    __syncthreads();

    for (int i = tid; i < TOK * NH; i += 256) {
        float* p = &y_s[0][0];
        p[i] = gelu_exact(p[i]);
    }
    __syncthreads();

    for (int i = tid; i < TOK * NH; i += 256) {
        const int tok = i / NH;
        const int j   = i - tok * NH;
        float z = sw[j];
        #pragma unroll
        for (int h = 0; h < NH; ++h) z += y_s[tok][h] * w2[h * NH + j];
        dw_out[((long)blockIdx.x * TOK + tok) * NH + j] = z;
    }
}

// Kernel 2 v4: 8 tokens/block, register double-buffered prefetch across
// tokens; raw s_barrier + lgkmcnt(0) only (prefetch loads stay in flight
// across barriers). pre/post scales held in registers (fixed column/thread).
__global__ __launch_bounds__(512, 2)
void agg_kernel(const float* __restrict__ xs,
                const float* __restrict__ dw,
                const float* __restrict__ pre_scales,
                const float* __restrict__ post_scales,
                float* __restrict__ out) {
    const int tid  = threadIdx.x;
    const int wave = tid >> 6;
    const int lane = tid & 63;
    const int coff = tid * 4;          // column offset within a row

    __shared__ float red[8][NL];       // per-wave partials, layer sumsq
    __shared__ float red2[8][NC];      // per-wave partials, way sumsq
    __shared__ float dws[2][64];       // dw for cur/next token, [l*4+c] layout

    const long tok0 = (long)blockIdx.x * ATOK;

    // scales: column is fixed per thread -> load once into registers
    fx4 preR[NL], postR[NC];
    #pragma unroll
    for (int l = 0; l < NL; ++l)
        preR[l] = *(const fx4*)(pre_scales + (long)l * ND + coff);
    #pragma unroll
    for (int c = 0; c < NC; ++c)
        postR[c] = *(const fx4*)(post_scales + (long)c * ND + coff);

    fx4 xA[NL], xB[NL];
    // prologue: token tok0 into xA + its dw into dws[0] (transposed l*4+c)
    #pragma unroll
    for (int l = 0; l < NL; ++l)
        xA[l] = *(const fx4*)(xs + (long)l * BTD + tok0 * ND + coff);
    if (tid < NC * NL) {
        const int c = tid / NL, l = tid - c * NL;
        dws[0][l * 4 + c] = dw[tok0 * (NC * NL) + tid];
    }

    auto body = [&](fx4 (&xc)[NL], fx4 (&xn)[NL], const int t, const int cb) {
        // ---- prefetch next token (stays in flight across barriers) ----
        if (t + 1 < ATOK) {
            const long tokn = tok0 + t + 1;
            #pragma unroll
            for (int l = 0; l < NL; ++l)
                xn[l] = *(const fx4*)(xs + (long)l * BTD + tokn * ND + coff);
            if (tid < NC * NL) {
                const int c = tid / NL, l = tid - c * NL;
                dws[cb ^ 1][l * 4 + c] = dw[tokn * (NC * NL) + tid];
            }
        }
        const long tok = tok0 + t;

        // ---- per-layer sumsq, wave reduce ----
        #pragma unroll
        for (int l = 0; l < NL; ++l) {
            float v = xc[l].x*xc[l].x + xc[l].y*xc[l].y
                    + xc[l].z*xc[l].z + xc[l].w*xc[l].w;
            #pragma unroll
            for (int off = 32; off; off >>= 1) v += __shfl_xor(v, off);
            if (lane == 0) red[wave][l] = v;
        }
        asm volatile("s_waitcnt lgkmcnt(0)" ::: "memory");  // LDS only; vmcnt untouched
        __builtin_amdgcn_s_barrier();
        __builtin_amdgcn_sched_barrier(0);

        // ---- fold (broadcast LDS reads) -> rinv per layer ----
        float s[NL];
        #pragma unroll
        for (int l = 0; l < NL; ++l) s[l] = 0.f;
        #pragma unroll
        for (int w = 0; w < 8; ++w) {
            const fx4 r0 = *(const fx4*)&red[w][0];
            const fx4 r1 = *(const fx4*)&red[w][4];
            const fx4 r2 = *(const fx4*)&red[w][8];
            s[0] += r0.x; s[1]  += r0.y; s[2]  += r0.z; s[3]  += r0.w;
            s[4] += r1.x; s[5]  += r1.y; s[6]  += r1.z; s[7]  += r1.w;
            s[8] += r2.x; s[9]  += r2.y; s[10] += r2.z; s[11] += r2.w;
        }
        float rvv[NL];
        #pragma unroll
        for (int l = 0; l < NL; ++l) rvv[l] = rsqrtf(s[l] * (1.0f / ND) + 1e-6f);

        // ---- aggregate 4 ways ----
        fx4 acc0 = (fx4)(0.f), acc1 = (fx4)(0.f), acc2 = (fx4)(0.f), acc3 = (fx4)(0.f);
        #pragma unroll
        for (int l = 0; l < NL; ++l) {
            const fx4 w4 = *(const fx4*)&dws[cb][l * 4];    // LDS broadcast
            const fx4 xnm = xc[l] * rvv[l] * preR[l];
            acc0 += w4.x * xnm;
            acc1 += w4.y * xnm;
            acc2 += w4.z * xnm;
            acc3 += w4.w * xnm;
        }

        // ---- per-way sumsq, wave reduce ----
        {
            float q0 = acc0.x*acc0.x + acc0.y*acc0.y + acc0.z*acc0.z + acc0.w*acc0.w;
            float q1 = acc1.x*acc1.x + acc1.y*acc1.y + acc1.z*acc1.z + acc1.w*acc1.w;
            float q2 = acc2.x*acc2.x + acc2.y*acc2.y + acc2.z*acc2.z + acc2.w*acc2.w;
            float q3 = acc3.x*acc3.x + acc3.y*acc3.y + acc3.z*acc3.z + acc3.w*acc3.w;
            #pragma unroll
            for (int off = 32; off; off >>= 1) {
                q0 += __shfl_xor(q0, off);
                q1 += __shfl_xor(q1, off);
                q2 += __shfl_xor(q2, off);
                q3 += __shfl_xor(q3, off);
            }
            if (lane == 0) {
                red2[wave][0] = q0; red2[wave][1] = q1;
                red2[wave][2] = q2; red2[wave][3] = q3;
            }
        }
        asm volatile("s_waitcnt lgkmcnt(0)" ::: "memory");
        __builtin_amdgcn_s_barrier();
        __builtin_amdgcn_sched_barrier(0);

        float s2[NC];
        #pragma unroll
        for (int c = 0; c < NC; ++c) s2[c] = 0.f;
        #pragma unroll
        for (int w = 0; w < 8; ++w) {
            const fx4 r = *(const fx4*)&red2[w][0];
            s2[0] += r.x; s2[1] += r.y; s2[2] += r.z; s2[3] += r.w;
        }
        float r2[NC];
        #pragma unroll
        for (int c = 0; c < NC; ++c) r2[c] = rsqrtf(s2[c] * (1.0f / ND) + 1e-6f);

        // ---- out = rms(agg)*post + x_cur ----
        const fx4 xcur = xc[NL - 1];
        const fx4 o0 = acc0 * r2[0] * postR[0] + xcur;
        const fx4 o1 = acc1 * r2[1] * postR[1] + xcur;
        const fx4 o2 = acc2 * r2[2] * postR[2] + xcur;
        const fx4 o3 = acc3 * r2[3] * postR[3] + xcur;
        *(fx4*)(out + 0L * BTD + tok * ND + coff) = o0;
        *(fx4*)(out + 1L * BTD + tok * ND + coff) = o1;
        *(fx4*)(out + 2L * BTD + tok * ND + coff) = o2;
        *(fx4*)(out + 3L * BTD + tok * ND + coff) = o3;
    };

    #pragma unroll
    for (int tt = 0; tt < ATOK; tt += 2) {
        body(xA, xB, tt,     0);
        body(xB, xA, tt + 1, 1);
    }
}

extern "C" void kernel_launch(void* const* d_in, const int* in_sizes, int n_in,
                              void* d_out, int out_size, void* d_ws, size_t ws_size,
                              hipStream_t stream) {
    const float* xs   = (const float*)d_in[0];
    const float* w1   = (const float*)d_in[1];
    const float* w2   = (const float*)d_in[2];
    const float* sw   = (const float*)d_in[3];
    const float* pre  = (const float*)d_in[4];
    const float* post = (const float*)d_in[5];
    float* out   = (float*)d_out;
    float* dw_ws = (float*)d_ws;   // 4096*48 floats = 786 KB

    dw_kernel<<<NBT / TOK, 256, 0, stream>>>(xs, w1, w2, sw, dw_ws);
    agg_kernel<<<AGRID, 512, 0, stream>>>(xs, dw_ws, pre, post, out);
}

// Round 6
// 185.103 us; speedup vs baseline: 1.4520x; 1.4520x over previous
//
#include <hip/hip_runtime.h>
#include <math.h>

#define NL 12
#define NB 2
#define NT 2048
#define ND 2048
#define NC 4
#define NH 48
#define NBT (NB*NT)                 // 4096 tokens
#define BTD ((long)NBT*(long)ND)    // 8388608
#define TOK 8                       // tokens per block in dw_kernel
#define ATOK 8                      // tokens per block in agg_kernel
#define AGRID (NBT/ATOK)            // 512 blocks = 2 per CU, persistent

typedef float fx4 __attribute__((ext_vector_type(4)));

__device__ __forceinline__ float gelu_exact(float x) {
    return 0.5f * x * (1.0f + erff(x * 0.70710678118654752f));
}

// Kernel 1: dw[b,t,j] = (gelu(rms(x_cur) @ w1) @ w2)[j] + static_weight[j]
__global__ __launch_bounds__(256, 2)
void dw_kernel(const float* __restrict__ xs,
               const float* __restrict__ w1,
               const float* __restrict__ w2,
               const float* __restrict__ sw,
               float* __restrict__ dw_out) {
    __shared__ float xls[TOK][ND];      // 64 KB: 8 token rows of x_current
    __shared__ float rinv_s[TOK];
    __shared__ float y_s[TOK][NH];
    const int tid  = threadIdx.x;
    const int wave = tid >> 6;
    const int lane = tid & 63;

    const float* xcur = xs + (long)(NL - 1) * BTD + (long)blockIdx.x * TOK * ND;
    const float4* src = (const float4*)xcur;
    float4* dst = (float4*)&xls[0][0];
    #pragma unroll
    for (int i = 0; i < (TOK * ND / 4) / 256; ++i)
        dst[tid + i * 256] = src[tid + i * 256];
    __syncthreads();

    #pragma unroll
    for (int tt = 0; tt < 2; ++tt) {
        const int tok = wave * 2 + tt;
        float ss = 0.f;
        for (int d = lane; d < ND; d += 64) { float v = xls[tok][d]; ss += v * v; }
        #pragma unroll
        for (int off = 32; off; off >>= 1) ss += __shfl_xor(ss, off);
        if (lane == 0) rinv_s[tok] = rsqrtf(ss * (1.0f / ND) + 1e-6f);
    }
    __syncthreads();

    float rv[TOK];
    #pragma unroll
    for (int t = 0; t < TOK; ++t) rv[t] = rinv_s[t];

    float acc[TOK][12];
    #pragma unroll
    for (int t = 0; t < TOK; ++t)
        #pragma unroll
        for (int j = 0; j < 12; ++j) acc[t][j] = 0.f;

    const int h0 = wave * 12;
    for (int d = lane; d < ND; d += 64) {
        const float* wrow = w1 + (long)d * NH + h0;
        const float4 wA = *(const float4*)(wrow);
        const float4 wB = *(const float4*)(wrow + 4);
        const float4 wC = *(const float4*)(wrow + 8);
        #pragma unroll
        for (int t = 0; t < TOK; ++t) {
            const float xv = xls[t][d] * rv[t];
            acc[t][0]  += xv * wA.x; acc[t][1]  += xv * wA.y;
            acc[t][2]  += xv * wA.z; acc[t][3]  += xv * wA.w;
            acc[t][4]  += xv * wB.x; acc[t][5]  += xv * wB.y;
            acc[t][6]  += xv * wB.z; acc[t][7]  += xv * wB.w;
            acc[t][8]  += xv * wC.x; acc[t][9]  += xv * wC.y;
            acc[t][10] += xv * wC.z; acc[t][11] += xv * wC.w;
        }
    }
    #pragma unroll
    for (int t = 0; t < TOK; ++t)
        #pragma unroll
        for (int j = 0; j < 12; ++j) {
            float v = acc[t][j];
            #pragma unroll
            for (int off = 32; off; off >>= 1) v += __shfl_xor(v, off);
            acc[t][j] = v;
        }
    if (lane == 0) {
        #pragma unroll
        for (int t = 0; t < TOK; ++t)
            #pragma unroll
            for (int j = 0; j < 12; ++j)
                y_s[t][h0 + j] = acc[t][j];
    }
    __syncthreads();

    for (int i = tid; i < TOK * NH; i += 256) {
        float* p = &y_s[0][0];
        p[i] = gelu_exact(p[i]);
    }
    __syncthreads();

    for (int i = tid; i < TOK * NH; i += 256) {
        const int tok = i / NH;
        const int j   = i - tok * NH;
        float z = sw[j];
        #pragma unroll
        for (int h = 0; h < NH; ++h) z += y_s[tok][h] * w2[h * NH + j];
        dw_out[((long)blockIdx.x * TOK + tok) * NH + j] = z;
    }
}

// Kernel 2 v5: lean persistent 512-thread blocks, 8 tokens each.
// Single x buffer (48 VGPR), scales streamed from L2 per token, dw via
// LDS broadcast. Target <=128 VGPR -> 2 blocks/CU, 16 waves, no spill.
__global__ __launch_bounds__(512, 4)
void agg_kernel(const float* __restrict__ xs,
                const float* __restrict__ dw,
                const float* __restrict__ pre_scales,
                const float* __restrict__ post_scales,
                float* __restrict__ out) {
    const int tid  = threadIdx.x;
    const int wave = tid >> 6;
    const int lane = tid & 63;
    const int coff = tid * 4;          // fixed column slice per thread

    __shared__ float red[8][NL];       // per-wave partials, layer sumsq
    __shared__ float red2[8][NC];      // per-wave partials, way sumsq
    __shared__ float dws[NC * NL];     // current token's dw, [l*4+c]

    const long tok0 = (long)blockIdx.x * ATOK;

    #pragma unroll 1
    for (int t = 0; t < ATOK; ++t) {
        const long tok = tok0 + t;

        // dw for this token (48 threads), transposed to [l*4+c]
        if (tid < NC * NL) {
            const int c = tid / NL, l = tid - c * NL;
            dws[l * NC + c] = dw[tok * (NC * NL) + tid];
        }

        // load this token's 12 layer rows (48 VGPR)
        fx4 x[NL];
        #pragma unroll
        for (int l = 0; l < NL; ++l)
            x[l] = *(const fx4*)(xs + (long)l * BTD + tok * ND + coff);

        // per-layer sumsq, wave reduce
        #pragma unroll
        for (int l = 0; l < NL; ++l) {
            float v = x[l].x*x[l].x + x[l].y*x[l].y
                    + x[l].z*x[l].z + x[l].w*x[l].w;
            #pragma unroll
            for (int off = 32; off; off >>= 1) v += __shfl_xor(v, off);
            if (lane == 0) red[wave][l] = v;
        }
        __syncthreads();   // B1: red + dws visible

        // fold 8 wave partials (LDS broadcast reads) -> rinv per layer
        float rvv[NL];
        {
            float s[NL];
            #pragma unroll
            for (int l = 0; l < NL; ++l) s[l] = 0.f;
            #pragma unroll
            for (int w = 0; w < 8; ++w) {
                const fx4 r0 = *(const fx4*)&red[w][0];
                const fx4 r1 = *(const fx4*)&red[w][4];
                const fx4 r2 = *(const fx4*)&red[w][8];
                s[0] += r0.x; s[1]  += r0.y; s[2]  += r0.z; s[3]  += r0.w;
                s[4] += r1.x; s[5]  += r1.y; s[6]  += r1.z; s[7]  += r1.w;
                s[8] += r2.x; s[9]  += r2.y; s[10] += r2.z; s[11] += r2.w;
            }
            #pragma unroll
            for (int l = 0; l < NL; ++l) rvv[l] = rsqrtf(s[l] * (1.0f / ND) + 1e-6f);
        }

        // aggregate 4 ways; pre_scales streamed from L2
        fx4 acc0 = (fx4)(0.f), acc1 = (fx4)(0.f), acc2 = (fx4)(0.f), acc3 = (fx4)(0.f);
        #pragma unroll
        for (int l = 0; l < NL; ++l) {
            const fx4 p = *(const fx4*)(pre_scales + (long)l * ND + coff);
            const fx4 w4 = *(const fx4*)&dws[l * NC];      // LDS broadcast
            const fx4 xn = x[l] * rvv[l] * p;
            acc0 += w4.x * xn;
            acc1 += w4.y * xn;
            acc2 += w4.z * xn;
            acc3 += w4.w * xn;
        }

        // per-way sumsq, wave reduce
        {
            float q0 = acc0.x*acc0.x + acc0.y*acc0.y + acc0.z*acc0.z + acc0.w*acc0.w;
            float q1 = acc1.x*acc1.x + acc1.y*acc1.y + acc1.z*acc1.z + acc1.w*acc1.w;
            float q2 = acc2.x*acc2.x + acc2.y*acc2.y + acc2.z*acc2.z + acc2.w*acc2.w;
            float q3 = acc3.x*acc3.x + acc3.y*acc3.y + acc3.z*acc3.z + acc3.w*acc3.w;
            #pragma unroll
            for (int off = 32; off; off >>= 1) {
                q0 += __shfl_xor(q0, off);
                q1 += __shfl_xor(q1, off);
                q2 += __shfl_xor(q2, off);
                q3 += __shfl_xor(q3, off);
            }
            if (lane == 0) {
                red2[wave][0] = q0; red2[wave][1] = q1;
                red2[wave][2] = q2; red2[wave][3] = q3;
            }
        }
        __syncthreads();   // B2: red2 visible; after this, dws/red reusable

        float r2[NC];
        {
            float s2[NC];
            #pragma unroll
            for (int c = 0; c < NC; ++c) s2[c] = 0.f;
            #pragma unroll
            for (int w = 0; w < 8; ++w) {
                const fx4 r = *(const fx4*)&red2[w][0];
                s2[0] += r.x; s2[1] += r.y; s2[2] += r.z; s2[3] += r.w;
            }
            #pragma unroll
            for (int c = 0; c < NC; ++c) r2[c] = rsqrtf(s2[c] * (1.0f / ND) + 1e-6f);
        }

        // out = rms(agg) * post_scales + x_current; post streamed from L2
        const fx4 xcur = x[NL - 1];
        {
            const fx4 q0 = *(const fx4*)(post_scales + 0L * ND + coff);
            const fx4 q1 = *(const fx4*)(post_scales + 1L * ND + coff);
            const fx4 q2 = *(const fx4*)(post_scales + 2L * ND + coff);
            const fx4 q3 = *(const fx4*)(post_scales + 3L * ND + coff);
            const fx4 o0 = acc0 * r2[0] * q0 + xcur;
            const fx4 o1 = acc1 * r2[1] * q1 + xcur;
            const fx4 o2 = acc2 * r2[2] * q2 + xcur;
            const fx4 o3 = acc3 * r2[3] * q3 + xcur;
            __builtin_nontemporal_store(o0, (fx4*)(out + 0L * BTD + tok * ND + coff));
            __builtin_nontemporal_store(o1, (fx4*)(out + 1L * BTD + tok * ND + coff));
            __builtin_nontemporal_store(o2, (fx4*)(out + 2L * BTD + tok * ND + coff));
            __builtin_nontemporal_store(o3, (fx4*)(out + 3L * BTD + tok * ND + coff));
        }
    }
}

extern "C" void kernel_launch(void* const* d_in, const int* in_sizes, int n_in,
                              void* d_out, int out_size, void* d_ws, size_t ws_size,
                              hipStream_t stream) {
    const float* xs   = (const float*)d_in[0];
    const float* w1   = (const float*)d_in[1];
    const float* w2   = (const float*)d_in[2];
    const float* sw   = (const float*)d_in[3];
    const float* pre  = (const float*)d_in[4];
    const float* post = (const float*)d_in[5];
    float* out   = (float*)d_out;
    float* dw_ws = (float*)d_ws;   // 4096*48 floats = 786 KB

    dw_kernel<<<NBT / TOK, 256, 0, stream>>>(xs, w1, w2, sw, dw_ws);
    agg_kernel<<<AGRID, 512, 0, stream>>>(xs, dw_ws, pre, post, out);
}

// Round 7
// 171.242 us; speedup vs baseline: 1.5696x; 1.0809x over previous
//
#include <hip/hip_runtime.h>
#include <math.h>

#define NL 12
#define NB 2
#define NT 2048
#define ND 2048
#define NC 4
#define NH 48
#define NBT (NB*NT)                 // 4096 tokens
#define BTD ((long)NBT*(long)ND)    // 8388608
#define TOK 8                       // tokens per block in dw_kernel

__device__ __forceinline__ float gelu_exact(float x) {
    return 0.5f * x * (1.0f + erff(x * 0.70710678118654752f));
}

// Kernel 1: dw[b,t,j] = (gelu(rms(x_cur) @ w1) @ w2)[j] + static_weight[j]
__global__ __launch_bounds__(256, 2)
void dw_kernel(const float* __restrict__ xs,
               const float* __restrict__ w1,
               const float* __restrict__ w2,
               const float* __restrict__ sw,
               float* __restrict__ dw_out) {
    __shared__ float xls[TOK][ND];      // 64 KB: 8 token rows of x_current
    __shared__ float rinv_s[TOK];
    __shared__ float y_s[TOK][NH];
    const int tid  = threadIdx.x;
    const int wave = tid >> 6;
    const int lane = tid & 63;

    const float* xcur = xs + (long)(NL - 1) * BTD + (long)blockIdx.x * TOK * ND;
    const float4* src = (const float4*)xcur;
    float4* dst = (float4*)&xls[0][0];
    #pragma unroll
    for (int i = 0; i < (TOK * ND / 4) / 256; ++i)
        dst[tid + i * 256] = src[tid + i * 256];
    __syncthreads();

    #pragma unroll
    for (int tt = 0; tt < 2; ++tt) {
        const int tok = wave * 2 + tt;
        float ss = 0.f;
        for (int d = lane; d < ND; d += 64) { float v = xls[tok][d]; ss += v * v; }
        #pragma unroll
        for (int off = 32; off; off >>= 1) ss += __shfl_xor(ss, off);
        if (lane == 0) rinv_s[tok] = rsqrtf(ss * (1.0f / ND) + 1e-6f);
    }
    __syncthreads();

    float rv[TOK];
    #pragma unroll
    for (int t = 0; t < TOK; ++t) rv[t] = rinv_s[t];

    float acc[TOK][12];
    #pragma unroll
    for (int t = 0; t < TOK; ++t)
        #pragma unroll
        for (int j = 0; j < 12; ++j) acc[t][j] = 0.f;

    const int h0 = wave * 12;
    for (int d = lane; d < ND; d += 64) {
        const float* wrow = w1 + (long)d * NH + h0;
        const float4 wA = *(const float4*)(wrow);
        const float4 wB = *(const float4*)(wrow + 4);
        const float4 wC = *(const float4*)(wrow + 8);
        #pragma unroll
        for (int t = 0; t < TOK; ++t) {
            const float xv = xls[t][d] * rv[t];
            acc[t][0]  += xv * wA.x; acc[t][1]  += xv * wA.y;
            acc[t][2]  += xv * wA.z; acc[t][3]  += xv * wA.w;
            acc[t][4]  += xv * wB.x; acc[t][5]  += xv * wB.y;
            acc[t][6]  += xv * wB.z; acc[t][7]  += xv * wB.w;
            acc[t][8]  += xv * wC.x; acc[t][9]  += xv * wC.y;
            acc[t][10] += xv * wC.z; acc[t][11] += xv * wC.w;
        }
    }
    #pragma unroll
    for (int t = 0; t < TOK; ++t)
        #pragma unroll
        for (int j = 0; j < 12; ++j) {
            float v = acc[t][j];
            #pragma unroll
            for (int off = 32; off; off >>= 1) v += __shfl_xor(v, off);
            acc[t][j] = v;
        }
    if (lane == 0) {
        #pragma unroll
        for (int t = 0; t < TOK; ++t)
            #pragma unroll
            for (int j = 0; j < 12; ++j)
                y_s[t][h0 + j] = acc[t][j];
    }
    __syncthreads();

    for (int i = tid; i < TOK * NH; i += 256) {
        float* p = &y_s[0][0];
        p[i] = gelu_exact(p[i]);
    }
    __syncthreads();

    for (int i = tid; i < TOK * NH; i += 256) {
        const int tok = i / NH;
        const int j   = i - tok * NH;
        float z = sw[j];
        #pragma unroll
        for (int h = 0; h < NH; ++h) z += y_s[tok][h] * w2[h * NH + j];
        dw_out[((long)blockIdx.x * TOK + tok) * NH + j] = z;
    }
}

// Kernel 2: R1 champion structure (token per 256-thread block, x held in
// registers, 4 barriers) with ONE change: launch_bounds (256,2)->(256,3)
// for 3 resident blocks/CU (12 waves) to destagger load/compute phases.
__global__ __launch_bounds__(256, 3)
void agg_kernel(const float* __restrict__ xs,
                const float* __restrict__ dw,
                const float* __restrict__ pre_scales,
                const float* __restrict__ post_scales,
                float* __restrict__ out) {
    const int tid  = threadIdx.x;
    const int wave = tid >> 6;
    const int lane = tid & 63;
    const long token = blockIdx.x;

    __shared__ float dw_s[NC * NL];
    __shared__ float rinv_s[NL];
    __shared__ float rinv2_s[NC];
    __shared__ float red[4][NL];
    __shared__ float red2[4][NC];

    if (tid < NC * NL) dw_s[tid] = dw[token * NC * NL + tid];

    // load all 12 layer rows for this token: 2 float4 per layer per thread
    float4 x[NL][2];
    #pragma unroll
    for (int l = 0; l < NL; ++l) {
        const float4* p = (const float4*)(xs + (long)l * BTD + token * ND);
        x[l][0] = p[tid];
        x[l][1] = p[tid + 256];
    }

    // per-layer sumsq
    float ss[NL];
    #pragma unroll
    for (int l = 0; l < NL; ++l) {
        const float4 a = x[l][0], b = x[l][1];
        ss[l] = a.x*a.x + a.y*a.y + a.z*a.z + a.w*a.w
              + b.x*b.x + b.y*b.y + b.z*b.z + b.w*b.w;
    }
    #pragma unroll
    for (int l = 0; l < NL; ++l) {
        float v = ss[l];
        #pragma unroll
        for (int off = 32; off; off >>= 1) v += __shfl_xor(v, off);
        if (lane == 0) red[wave][l] = v;
    }
    __syncthreads();
    if (tid < NL) {
        const float s = red[0][tid] + red[1][tid] + red[2][tid] + red[3][tid];
        rinv_s[tid] = rsqrtf(s * (1.0f / ND) + 1e-6f);
    }
    __syncthreads();

    float rvv[NL];
    #pragma unroll
    for (int l = 0; l < NL; ++l) rvv[l] = rinv_s[l];

    // aggregate 4 ways
    float4 acc[NC][2];
    #pragma unroll
    for (int c = 0; c < NC; ++c) {
        acc[c][0] = make_float4(0.f, 0.f, 0.f, 0.f);
        acc[c][1] = make_float4(0.f, 0.f, 0.f, 0.f);
    }
    #pragma unroll
    for (int l = 0; l < NL; ++l) {
        const float rv = rvv[l];
        const float4* ps = (const float4*)(pre_scales + (long)l * ND);
        const float4 p0 = ps[tid];
        const float4 p1 = ps[tid + 256];
        float4 xn0, xn1;
        xn0.x = x[l][0].x * rv * p0.x;  xn0.y = x[l][0].y * rv * p0.y;
        xn0.z = x[l][0].z * rv * p0.z;  xn0.w = x[l][0].w * rv * p0.w;
        xn1.x = x[l][1].x * rv * p1.x;  xn1.y = x[l][1].y * rv * p1.y;
        xn1.z = x[l][1].z * rv * p1.z;  xn1.w = x[l][1].w * rv * p1.w;
        #pragma unroll
        for (int c = 0; c < NC; ++c) {
            const float w = dw_s[c * NL + l];
            acc[c][0].x += w * xn0.x;  acc[c][0].y += w * xn0.y;
            acc[c][0].z += w * xn0.z;  acc[c][0].w += w * xn0.w;
            acc[c][1].x += w * xn1.x;  acc[c][1].y += w * xn1.y;
            acc[c][1].z += w * xn1.z;  acc[c][1].w += w * xn1.w;
        }
    }

    // sumsq of agg per way
    float ss2[NC];
    #pragma unroll
    for (int c = 0; c < NC; ++c) {
        const float4 a = acc[c][0], b = acc[c][1];
        ss2[c] = a.x*a.x + a.y*a.y + a.z*a.z + a.w*a.w
               + b.x*b.x + b.y*b.y + b.z*b.z + b.w*b.w;
    }
    #pragma unroll
    for (int c = 0; c < NC; ++c) {
        float v = ss2[c];
        #pragma unroll
        for (int off = 32; off; off >>= 1) v += __shfl_xor(v, off);
        if (lane == 0) red2[wave][c] = v;
    }
    __syncthreads();
    if (tid < NC) {
        const float s = red2[0][tid] + red2[1][tid] + red2[2][tid] + red2[3][tid];
        rinv2_s[tid] = rsqrtf(s * (1.0f / ND) + 1e-6f);
    }
    __syncthreads();

    // out = rms(agg) * post_scales + x_current
    #pragma unroll
    for (int c = 0; c < NC; ++c) {
        const float r2 = rinv2_s[c];
        const float4* po = (const float4*)(post_scales + (long)c * ND);
        const float4 q0 = po[tid];
        const float4 q1 = po[tid + 256];
        float4 o0, o1;
        o0.x = acc[c][0].x * r2 * q0.x + x[NL-1][0].x;
        o0.y = acc[c][0].y * r2 * q0.y + x[NL-1][0].y;
        o0.z = acc[c][0].z * r2 * q0.z + x[NL-1][0].z;
        o0.w = acc[c][0].w * r2 * q0.w + x[NL-1][0].w;
        o1.x = acc[c][1].x * r2 * q1.x + x[NL-1][1].x;
        o1.y = acc[c][1].y * r2 * q1.y + x[NL-1][1].y;
        o1.z = acc[c][1].z * r2 * q1.z + x[NL-1][1].z;
        o1.w = acc[c][1].w * r2 * q1.w + x[NL-1][1].w;
        float4* op = (float4*)(out + (long)c * BTD + token * ND);
        op[tid]       = o0;
        op[tid + 256] = o1;
    }
}

extern "C" void kernel_launch(void* const* d_in, const int* in_sizes, int n_in,
                              void* d_out, int out_size, void* d_ws, size_t ws_size,
                              hipStream_t stream) {
    const float* xs   = (const float*)d_in[0];
    const float* w1   = (const float*)d_in[1];
    const float* w2   = (const float*)d_in[2];
    const float* sw   = (const float*)d_in[3];
    const float* pre  = (const float*)d_in[4];
    const float* post = (const float*)d_in[5];
    float* out   = (float*)d_out;
    float* dw_ws = (float*)d_ws;   // 4096*48 floats = 786 KB

    dw_kernel<<<NBT / TOK, 256, 0, stream>>>(xs, w1, w2, sw, dw_ws);
    agg_kernel<<<NBT, 256, 0, stream>>>(xs, dw_ws, pre, post, out);
}